// Round 1
// baseline (94.819 us; speedup 1.0000x reference)
//
#include <hip/hip_runtime.h>
#include <hip/hip_bf16.h>

// Positional encoder: out[n, c, s, d] with s=0 -> sin(x[n,c]*2^d), s=1 -> cos(...)
// d in [0,10). Output row = 60 floats: [c0: sin d0..9, cos d0..9][c1: ...][c2: ...].
//
// Strategy: memory-bound (24 MB read, 480 MB write). One thread per input
// element (n,c); compute 10 sin + 10 cos via hardware v_sin/v_cos (revolutions
// + v_fract range reduction), stage the 20 contiguous outputs in LDS, then
// drain the block's 15360 B as fully coalesced float4 stores.

#define ENC_BLOCK 192          // 192 threads = 64 whole rows (3 ch) per block
#define ENC_PER 20             // outputs per input element

__global__ __launch_bounds__(ENC_BLOCK)
void Encoder_65077344469353_kernel(const float* __restrict__ x,
                                   float* __restrict__ out,
                                   int n_elem) {
    __shared__ float lds[ENC_BLOCK * ENC_PER];   // 15360 B

    const int t = threadIdx.x;
    const long long base = (long long)blockIdx.x * ENC_BLOCK;   // element index base
    const long long e = base + t;

    float xv = 0.0f;
    if (e < n_elem) xv = x[e];                    // coalesced: 4 B/lane

    // revolutions = phase / (2*pi); scaling by 2^d is exact in fp32
    const float INV2PI = 0.15915494309189535f;
    float rv = xv * INV2PI;

    float* dst = &lds[t * ENC_PER];               // byte offset 80*t (16B aligned)
    #pragma unroll
    for (int d = 0; d < 10; ++d) {
        float r = __builtin_amdgcn_fractf(rv);    // range-reduce to [0,1) rev
        dst[d]      = __builtin_amdgcn_sinf(r);   // sin(2*pi*r)
        dst[10 + d] = __builtin_amdgcn_cosf(r);   // cos(2*pi*r)
        rv *= 2.0f;                               // exact
    }
    __syncthreads();

    // Drain LDS -> global, fully coalesced float4.
    const long long out_base_f = base * ENC_PER;              // float index
    const long long out_total_f = (long long)n_elem * ENC_PER;
    const float4* lds4 = (const float4*)lds;
    float4* out4 = (float4*)(out + out_base_f);               // 16B aligned (80*base)
    #pragma unroll
    for (int i = 0; i < 5; ++i) {
        int j = i * ENC_BLOCK + t;                            // 0..959
        if (out_base_f + (long long)j * 4 < out_total_f)
            out4[j] = lds4[j];
    }
}

extern "C" void kernel_launch(void* const* d_in, const int* in_sizes, int n_in,
                              void* d_out, int out_size, void* d_ws, size_t ws_size,
                              hipStream_t stream) {
    const float* x = (const float*)d_in[0];
    float* out = (float*)d_out;
    const int n_elem = in_sizes[0];               // N*3 flat input elements
    const int blocks = (n_elem + ENC_BLOCK - 1) / ENC_BLOCK;
    Encoder_65077344469353_kernel<<<dim3(blocks), dim3(ENC_BLOCK), 0, stream>>>(
        x, out, n_elem);
}